// Round 1
// baseline (1260.455 us; speedup 1.0000x reference)
//
#include <hip/hip_runtime.h>
#include <math.h>

#define HIDDEN 2048
#define INTER  5632
#define TOKENS 8192

typedef __attribute__((ext_vector_type(8))) short bf16x8;
typedef __attribute__((ext_vector_type(4))) float f32x4;
typedef __attribute__((ext_vector_type(4))) short short4v;

__device__ __forceinline__ short f2bf(float f) {
  union { float f; unsigned u; } v; v.f = f;
  unsigned r = v.u + 0x7fffu + ((v.u >> 16) & 1u);
  return (short)(r >> 16);
}

// ---------------- fp32 -> bf16 weight cast ----------------
__global__ __launch_bounds__(256) void cvt_w(const float* __restrict__ src,
                                             short* __restrict__ dst, int n4) {
  int i = blockIdx.x * 256 + threadIdx.x;
  if (i >= n4) return;
  float4 v = ((const float4*)src)[i];
  short4v o;
  o[0] = f2bf(v.x); o[1] = f2bf(v.y); o[2] = f2bf(v.z); o[3] = f2bf(v.w);
  ((short4v*)dst)[i] = o;
}

// ---------------- FWHT per row (x @ H^T == FWHT(x)/sqrt(H)) + bf16 cast ----------------
__global__ __launch_bounds__(256) void fwht_cast(const float* __restrict__ X,
                                                 short* __restrict__ Xr) {
  __shared__ __align__(16) float row[HIDDEN];
  const int tid = threadIdx.x;
  for (int r = blockIdx.x; r < TOKENS; r += gridDim.x) {
    const float4* src = (const float4*)(X + (size_t)r * HIDDEN);
    float4 va = src[tid];        // elems 4*tid .. 4*tid+3
    float4 vb = src[tid + 256];  // elems 1024+4*tid .. +3
    float a[8] = {va.x, va.y, va.z, va.w, vb.x, vb.y, vb.z, vb.w};
    // stride-1024 butterflies (a[j] vs a[j+4])
    #pragma unroll
    for (int j = 0; j < 4; ++j) { float s = a[j] + a[j+4], d = a[j] - a[j+4]; a[j] = s; a[j+4] = d; }
    // stride-1
    #pragma unroll
    for (int j = 0; j < 8; j += 2) { float s = a[j] + a[j+1], d = a[j] - a[j+1]; a[j] = s; a[j+1] = d; }
    // stride-2
    #pragma unroll
    for (int h = 0; h < 8; h += 4) {
      { float s = a[h]   + a[h+2], d = a[h]   - a[h+2]; a[h]   = s; a[h+2] = d; }
      { float s = a[h+1] + a[h+3], d = a[h+1] - a[h+3]; a[h+1] = s; a[h+3] = d; }
    }
    ((float4*)row)[tid]       = make_float4(a[0], a[1], a[2], a[3]);
    ((float4*)row)[tid + 256] = make_float4(a[4], a[5], a[6], a[7]);
    __syncthreads();
    // strides 4..512 in LDS
    for (int s = 4; s <= 512; s <<= 1) {
      #pragma unroll
      for (int pp = 0; pp < 4; ++pp) {
        int p = tid + pp * 256;
        int i = ((p & ~(s - 1)) << 1) | (p & (s - 1));
        float x0 = row[i], x1 = row[i + s];
        row[i] = x0 + x1; row[i + s] = x0 - x1;
      }
      __syncthreads();
    }
    const float scale = 0.02209708691207961f; // 1/sqrt(2048)
    float4 wa = ((float4*)row)[tid];
    float4 wb = ((float4*)row)[tid + 256];
    short4v oa, ob;
    oa[0] = f2bf(wa.x * scale); oa[1] = f2bf(wa.y * scale);
    oa[2] = f2bf(wa.z * scale); oa[3] = f2bf(wa.w * scale);
    ob[0] = f2bf(wb.x * scale); ob[1] = f2bf(wb.y * scale);
    ob[2] = f2bf(wb.z * scale); ob[3] = f2bf(wb.w * scale);
    short* dst = Xr + (size_t)r * HIDDEN;
    ((short4v*)dst)[tid]       = oa;
    ((short4v*)dst)[tid + 256] = ob;
    __syncthreads(); // protect LDS reuse on next grid-stride row
  }
}

// ---------------- GEMM helpers ----------------
// Stage a 128x64 bf16 tile (row-major, leading dim ldK elements) into LDS
// laid out linearly as [128][64]. 256 threads, 4 iters of 32 rows,
// global_load_lds width 16 (lane-linear LDS destination).
__device__ __forceinline__ void stage_tile(const short* __restrict__ gsrc, int ldK,
                                           short* lds, int tid) {
  const int wave = tid >> 6;
  #pragma unroll
  for (int it = 0; it < 4; ++it) {
    const short* gp = gsrc + (size_t)(it * 32 + (tid >> 3)) * ldK + (tid & 7) * 8;
    short* lp = lds + it * 2048 + wave * 512; // wave-uniform base; HW adds lane*16B
    __builtin_amdgcn_global_load_lds((const __attribute__((address_space(1))) void*)gp,
                                     (__attribute__((address_space(3))) void*)lp,
                                     16, 0, 0);
  }
}

// ---------------- fused gate/up GEMM + SwiGLU epilogue ----------------
// A: xr bf16 [TOKENS,HIDDEN]; Bg/Bu: bf16 [INTER,HIDDEN]; Hb: bf16 [TOKENS,INTER]
__global__ __launch_bounds__(256) void gemm_gateup(const short* __restrict__ A,
                                                   const short* __restrict__ Bg,
                                                   const short* __restrict__ Bu,
                                                   short* __restrict__ Hb) {
  constexpr int Kn = HIDDEN, Nn = INTER;
  constexpr int nbn = INTER / 128;            // 44
  constexpr int nwg = (TOKENS / 128) * nbn;   // 2816 (%8 == 0)
  __shared__ __align__(16) short As[128 * 64];
  __shared__ __align__(16) short Bgs[128 * 64];
  __shared__ __align__(16) short Bus[128 * 64];

  const int bid = blockIdx.x;
  const int swz = (bid & 7) * (nwg >> 3) + (bid >> 3); // XCD-aware swizzle
  const int bm = swz / nbn, bn = swz % nbn;

  const int tid = threadIdx.x;
  const int lane = tid & 63, wave = tid >> 6;
  const int wr = wave >> 1, wc = wave & 1;   // 2x2 waves, 64x64 each
  const int fr = lane & 15, fq = lane >> 4;

  f32x4 accG[4][4] = {};
  f32x4 accU[4][4] = {};

  const short* Ab  = A  + (size_t)bm * 128 * Kn;
  const short* Bgb = Bg + (size_t)bn * 128 * Kn;
  const short* Bub = Bu + (size_t)bn * 128 * Kn;

  for (int kt = 0; kt < Kn; kt += 64) {
    __syncthreads();
    stage_tile(Ab + kt, Kn, As, tid);
    stage_tile(Bgb + kt, Kn, Bgs, tid);
    stage_tile(Bub + kt, Kn, Bus, tid);
    __syncthreads();
    #pragma unroll
    for (int kk = 0; kk < 64; kk += 32) {
      bf16x8 af[4], bgf[4], buf_[4];
      #pragma unroll
      for (int i = 0; i < 4; ++i)
        af[i] = *(const bf16x8*)(As + (wr * 64 + i * 16 + fr) * 64 + kk + fq * 8);
      #pragma unroll
      for (int j = 0; j < 4; ++j) {
        bgf[j]  = *(const bf16x8*)(Bgs + (wc * 64 + j * 16 + fr) * 64 + kk + fq * 8);
        buf_[j] = *(const bf16x8*)(Bus + (wc * 64 + j * 16 + fr) * 64 + kk + fq * 8);
      }
      #pragma unroll
      for (int i = 0; i < 4; ++i) {
        #pragma unroll
        for (int j = 0; j < 4; ++j) {
          accG[i][j] = __builtin_amdgcn_mfma_f32_16x16x32_bf16(af[i], bgf[j],  accG[i][j], 0, 0, 0);
          accU[i][j] = __builtin_amdgcn_mfma_f32_16x16x32_bf16(af[i], buf_[j], accU[i][j], 0, 0, 0);
        }
      }
    }
  }

  // epilogue: h = silu(g)*u, bf16
  #pragma unroll
  for (int i = 0; i < 4; ++i) {
    #pragma unroll
    for (int j = 0; j < 4; ++j) {
      const int grow = bm * 128 + wr * 64 + i * 16 + fq * 4;
      const int gcol = bn * 128 + wc * 64 + j * 16 + fr;
      #pragma unroll
      for (int ii = 0; ii < 4; ++ii) {
        float g = accG[i][j][ii];
        float u = accU[i][j][ii];
        float h = g * u / (1.0f + __expf(-g));
        Hb[(size_t)(grow + ii) * Nn + gcol] = f2bf(h);
      }
    }
  }
}

// ---------------- down GEMM, fp32 output ----------------
// A: h bf16 [TOKENS,INTER]; B: down bf16 [HIDDEN,INTER]; Out: fp32 [TOKENS,HIDDEN]
__global__ __launch_bounds__(256) void gemm_down(const short* __restrict__ A,
                                                 const short* __restrict__ B,
                                                 float* __restrict__ Out) {
  constexpr int Kn = INTER, Nn = HIDDEN;
  constexpr int nbn = HIDDEN / 128;           // 16
  constexpr int nwg = (TOKENS / 128) * nbn;   // 1024 (%8 == 0)
  __shared__ __align__(16) short As[128 * 64];
  __shared__ __align__(16) short Bs[128 * 64];

  const int bid = blockIdx.x;
  const int swz = (bid & 7) * (nwg >> 3) + (bid >> 3);
  const int bm = swz / nbn, bn = swz % nbn;

  const int tid = threadIdx.x;
  const int lane = tid & 63, wave = tid >> 6;
  const int wr = wave >> 1, wc = wave & 1;
  const int fr = lane & 15, fq = lane >> 4;

  f32x4 acc[4][4] = {};

  const short* Ab = A + (size_t)bm * 128 * Kn;
  const short* Bb = B + (size_t)bn * 128 * Kn;

  for (int kt = 0; kt < Kn; kt += 64) {
    __syncthreads();
    stage_tile(Ab + kt, Kn, As, tid);
    stage_tile(Bb + kt, Kn, Bs, tid);
    __syncthreads();
    #pragma unroll
    for (int kk = 0; kk < 64; kk += 32) {
      bf16x8 af[4], bf[4];
      #pragma unroll
      for (int i = 0; i < 4; ++i)
        af[i] = *(const bf16x8*)(As + (wr * 64 + i * 16 + fr) * 64 + kk + fq * 8);
      #pragma unroll
      for (int j = 0; j < 4; ++j)
        bf[j] = *(const bf16x8*)(Bs + (wc * 64 + j * 16 + fr) * 64 + kk + fq * 8);
      #pragma unroll
      for (int i = 0; i < 4; ++i) {
        #pragma unroll
        for (int j = 0; j < 4; ++j)
          acc[i][j] = __builtin_amdgcn_mfma_f32_16x16x32_bf16(af[i], bf[j], acc[i][j], 0, 0, 0);
      }
    }
  }

  #pragma unroll
  for (int i = 0; i < 4; ++i) {
    #pragma unroll
    for (int j = 0; j < 4; ++j) {
      const int grow = bm * 128 + wr * 64 + i * 16 + fq * 4;
      const int gcol = bn * 128 + wc * 64 + j * 16 + fr;
      #pragma unroll
      for (int ii = 0; ii < 4; ++ii)
        Out[(size_t)(grow + ii) * Nn + gcol] = acc[i][j][ii];
    }
  }
}

extern "C" void kernel_launch(void* const* d_in, const int* in_sizes, int n_in,
                              void* d_out, int out_size, void* d_ws, size_t ws_size,
                              hipStream_t stream) {
  const float* x      = (const float*)d_in[0];
  // d_in[1] = H (Sylvester Hadamard; symmetric -> computed via FWHT, unused)
  const float* gate_w = (const float*)d_in[2];
  const float* up_w   = (const float*)d_in[3];
  const float* down_w = (const float*)d_in[4];
  float* out = (float*)d_out;

  short* xr = (short*)d_ws;                       // [TOKENS, HIDDEN] bf16
  short* gw = xr + (size_t)TOKENS * HIDDEN;       // [INTER, HIDDEN] bf16
  short* uw = gw + (size_t)INTER * HIDDEN;        // [INTER, HIDDEN] bf16
  short* dw = uw + (size_t)INTER * HIDDEN;        // [HIDDEN, INTER] bf16
  short* hb = dw + (size_t)HIDDEN * INTER;        // [TOKENS, INTER] bf16

  const int n4 = (INTER * HIDDEN) / 4;            // 2,883,584
  cvt_w<<<(n4 + 255) / 256, 256, 0, stream>>>(gate_w, gw, n4);
  cvt_w<<<(n4 + 255) / 256, 256, 0, stream>>>(up_w, uw, n4);
  cvt_w<<<(n4 + 255) / 256, 256, 0, stream>>>(down_w, dw, n4);

  fwht_cast<<<2048, 256, 0, stream>>>(x, xr);

  gemm_gateup<<<(TOKENS / 128) * (INTER / 128), 256, 0, stream>>>(xr, gw, uw, hb);
  gemm_down<<<(TOKENS / 128) * (HIDDEN / 128), 256, 0, stream>>>(hb, dw, out);
}

// Round 3
// 719.862 us; speedup vs baseline: 1.7510x; 1.7510x over previous
//
#include <hip/hip_runtime.h>
#include <math.h>

#define HIDDEN 2048
#define INTER  5632
#define TOKENS 8192

typedef __attribute__((ext_vector_type(8))) short bf16x8;
typedef __attribute__((ext_vector_type(4))) float f32x4;
typedef __attribute__((ext_vector_type(4))) short short4v;

#define FENCE() asm volatile("" ::: "memory")
#define BAR()   __builtin_amdgcn_s_barrier()
#define LGKM0() asm volatile("s_waitcnt lgkmcnt(0)" ::: "memory")
#define SCHED0() __builtin_amdgcn_sched_barrier(0)
#define VMCNT(n) asm volatile("s_waitcnt vmcnt(" #n ")" ::: "memory")

__device__ __forceinline__ short f2bf(float f) {
  union { float f; unsigned u; } v; v.f = f;
  unsigned r = v.u + 0x7fffu + ((v.u >> 16) & 1u);
  return (short)(r >> 16);
}
__device__ __forceinline__ float bf2f(short s) {
  union { unsigned u; float f; } v; v.u = ((unsigned)(unsigned short)s) << 16;
  return v.f;
}

// ---------------- fp32 -> bf16 weight cast ----------------
__global__ __launch_bounds__(256) void cvt_w(const float* __restrict__ src,
                                             short* __restrict__ dst, int n4) {
  int i = blockIdx.x * 256 + threadIdx.x;
  if (i >= n4) return;
  float4 v = ((const float4*)src)[i];
  short4v o;
  o[0] = f2bf(v.x); o[1] = f2bf(v.y); o[2] = f2bf(v.z); o[3] = f2bf(v.w);
  ((short4v*)dst)[i] = o;
}

// ---------------- FWHT per row (x @ H^T == FWHT(x)/sqrt(H)) + bf16 cast ----------------
__global__ __launch_bounds__(256) void fwht_cast(const float* __restrict__ X,
                                                 short* __restrict__ Xr) {
  __shared__ __align__(16) float row[HIDDEN];
  const int tid = threadIdx.x;
  for (int r = blockIdx.x; r < TOKENS; r += gridDim.x) {
    const float4* src = (const float4*)(X + (size_t)r * HIDDEN);
    float4 va = src[tid];
    float4 vb = src[tid + 256];
    float a[8] = {va.x, va.y, va.z, va.w, vb.x, vb.y, vb.z, vb.w};
    #pragma unroll
    for (int j = 0; j < 4; ++j) { float s = a[j] + a[j+4], d = a[j] - a[j+4]; a[j] = s; a[j+4] = d; }
    #pragma unroll
    for (int j = 0; j < 8; j += 2) { float s = a[j] + a[j+1], d = a[j] - a[j+1]; a[j] = s; a[j+1] = d; }
    #pragma unroll
    for (int h = 0; h < 8; h += 4) {
      { float s = a[h]   + a[h+2], d = a[h]   - a[h+2]; a[h]   = s; a[h+2] = d; }
      { float s = a[h+1] + a[h+3], d = a[h+1] - a[h+3]; a[h+1] = s; a[h+3] = d; }
    }
    ((float4*)row)[tid]       = make_float4(a[0], a[1], a[2], a[3]);
    ((float4*)row)[tid + 256] = make_float4(a[4], a[5], a[6], a[7]);
    __syncthreads();
    for (int s = 4; s <= 512; s <<= 1) {
      #pragma unroll
      for (int pp = 0; pp < 4; ++pp) {
        int p = tid + pp * 256;
        int i = ((p & ~(s - 1)) << 1) | (p & (s - 1));
        float x0 = row[i], x1 = row[i + s];
        row[i] = x0 + x1; row[i + s] = x0 - x1;
      }
      __syncthreads();
    }
    const float scale = 0.02209708691207961f; // 1/sqrt(2048)
    float4 wa = ((float4*)row)[tid];
    float4 wb = ((float4*)row)[tid + 256];
    short4v oa, ob;
    oa[0] = f2bf(wa.x * scale); oa[1] = f2bf(wa.y * scale);
    oa[2] = f2bf(wa.z * scale); oa[3] = f2bf(wa.w * scale);
    ob[0] = f2bf(wb.x * scale); ob[1] = f2bf(wb.y * scale);
    ob[2] = f2bf(wb.z * scale); ob[3] = f2bf(wb.w * scale);
    short* dst = Xr + (size_t)r * HIDDEN;
    ((short4v*)dst)[tid]       = oa;
    ((short4v*)dst)[tid + 256] = ob;
    __syncthreads();
  }
}

// ---------------- 256x256 8-phase GEMM (B^T layout: C[m][n] = sum_k A[m][k]*B[n][k]) ----
// LDS regions per buffer: 0 = A rows 0..127, 1 = A rows 128..255, 2 = B rows 0..127,
// 3 = B rows 128..255. Each region [128][64] bf16, 16B-chunk XOR-swizzled by (row&7):
// LDS slot (row, c) holds global chunk (c ^ (row&7)).  global_load_lds dest stays linear.
__device__ __forceinline__ void stage_half(const short* __restrict__ gbase, int ldK, int kt,
                                           short* region, int tid) {
  const int w = tid >> 6;
  #pragma unroll
  for (int j = 0; j < 2; ++j) {
    const int slot = tid + j * 512;
    const int row  = slot >> 3;
    const int cg   = (slot & 7) ^ (row & 7);
    const short* gp = gbase + (size_t)row * ldK + kt * 64 + cg * 8;
    short* lp = region + w * 512 + j * 4096;   // wave-uniform base; HW adds lane*16B
    __builtin_amdgcn_global_load_lds((const __attribute__((address_space(1))) void*)gp,
                                     (__attribute__((address_space(3))) void*)lp, 16, 0, 0);
  }
}

__device__ __forceinline__ void ldsA(const short* rg, int qm, int fr, const int* cx,
                                     bf16x8* dst) {
  #pragma unroll
  for (int i = 0; i < 4; ++i)
    #pragma unroll
    for (int kk = 0; kk < 2; ++kk)
      dst[i * 2 + kk] = *(const bf16x8*)(rg + (qm * 64 + i * 16 + fr) * 64 + cx[kk]);
}

__device__ __forceinline__ void ldsB(const short* rg, int qn, int rb, int fr, const int* cx,
                                     bf16x8* dst) {
  #pragma unroll
  for (int n = 0; n < 2; ++n)
    #pragma unroll
    for (int kk = 0; kk < 2; ++kk)
      dst[n * 2 + kk] = *(const bf16x8*)(rg + (rb + qn * 32 + n * 16 + fr) * 64 + cx[kk]);
}

__device__ __forceinline__ void mfma16(const bf16x8* a, const bf16x8* b,
                                       f32x4 (&acc)[8][4], int qm, int qn) {
  #pragma unroll
  for (int i = 0; i < 4; ++i)
    #pragma unroll
    for (int n = 0; n < 2; ++n)
      #pragma unroll
      for (int kk = 0; kk < 2; ++kk)
        acc[qm * 4 + i][qn * 2 + n] = __builtin_amdgcn_mfma_f32_16x16x32_bf16(
            a[i * 2 + kk], b[n * 2 + kk], acc[qm * 4 + i][qn * 2 + n], 0, 0, 0);
}

// EPI: 0 = write f2bf(silu(v)); 1 = read bf16 C, write f2bf(v * C) (in place);
//      2 = write fp32 v.
template<int LDK, int NBN, int NOUT, int EPI>
__global__ __launch_bounds__(512, 2) void gemm256(const short* __restrict__ A,
                                                  const short* __restrict__ B,
                                                  void* __restrict__ Cv) {
  constexpr int NKT = LDK / 64;
  constexpr int NITER = NKT / 2;
  __shared__ __align__(16) short lds[2][4][8192];   // 128 KiB

  const int tid  = threadIdx.x;
  const int lane = tid & 63, wv = tid >> 6;
  const int wr = wv >> 2, wc = wv & 3;              // 2 x 4 waves, 128x64 out each
  const int fr = lane & 15, fq = lane >> 4;
  const int x7 = fr & 7;
  const int cx[2] = { (fq ^ x7) * 8, ((4 + fq) ^ x7) * 8 };
  const int rbB = (wc & 1) * 64;

  const int nwg = gridDim.x;                        // multiple of 8 for all instances
  const int swz = (blockIdx.x & 7) * (nwg >> 3) + (blockIdx.x >> 3);
  const int bm = swz / NBN, bn = swz % NBN;

  const short* Ab[2] = { A + (size_t)(bm * 256) * LDK, A + (size_t)(bm * 256 + 128) * LDK };
  const short* Bb[2] = { B + (size_t)(bn * 256) * LDK, B + (size_t)(bn * 256 + 128) * LDK };

#define STAGE(kt_, rg_) stage_half((rg_) < 2 ? Ab[(rg_)] : Bb[(rg_) - 2], LDK, (kt_), \
                                   &lds[(kt_) & 1][(rg_)][0], tid)

  f32x4 acc[8][4] = {};

  // prologue: tile0 full + tile1 halves 0..2 -> wait for tile0 (6 loads stay in flight)
  STAGE(0, 0); STAGE(0, 1); STAGE(0, 2); STAGE(0, 3);
  STAGE(1, 0); STAGE(1, 1); STAGE(1, 2);
  VMCNT(6);
  FENCE(); BAR();

  bf16x8 af0[8], af1[8], bf0[4], bf1[4];

  for (int it = 0; it < NITER; ++it) {
    const int e = 2 * it;
    const bool nl = (it < NITER - 1);
    const short* Ar0 = &lds[0][wr][0];
    const short* Br0 = &lds[0][2 + (wc >> 1)][0];
    const short* Ar1 = &lds[1][wr][0];
    const short* Br1 = &lds[1][2 + (wc >> 1)][0];

    // ---- tile e (buf0); phase order (qm,qn) = (0,0),(1,0),(1,1),(0,1) ----
    ldsA(Ar0, 0, fr, cx, af0);
    ldsB(Br0, 0, rbB, fr, cx, bf0);
    STAGE(e + 1, 3);
    FENCE(); BAR(); LGKM0(); SCHED0();
    __builtin_amdgcn_s_setprio(1); mfma16(af0, bf0, acc, 0, 0); __builtin_amdgcn_s_setprio(0);
    FENCE(); BAR();

    ldsA(Ar0, 1, fr, cx, af1);
    if (nl) STAGE(e + 2, 0);
    FENCE(); BAR(); LGKM0(); SCHED0();
    __builtin_amdgcn_s_setprio(1); mfma16(af1, bf0, acc, 1, 0); __builtin_amdgcn_s_setprio(0);
    FENCE(); BAR();

    ldsB(Br0, 1, rbB, fr, cx, bf1);
    if (nl) STAGE(e + 2, 1);
    FENCE(); BAR(); LGKM0(); SCHED0();
    __builtin_amdgcn_s_setprio(1); mfma16(af1, bf1, acc, 1, 1); __builtin_amdgcn_s_setprio(0);
    FENCE(); BAR();

    if (nl) STAGE(e + 2, 2);
    FENCE(); BAR(); LGKM0(); SCHED0();
    __builtin_amdgcn_s_setprio(1); mfma16(af0, bf1, acc, 0, 1); __builtin_amdgcn_s_setprio(0);
    if (nl) { VMCNT(6); } else { VMCNT(0); }   // tile e+1 now fully resident
    FENCE(); BAR();

    // ---- tile e+1 (buf1) ----
    ldsA(Ar1, 0, fr, cx, af0);
    ldsB(Br1, 0, rbB, fr, cx, bf0);
    if (nl) STAGE(e + 2, 3);
    FENCE(); BAR(); LGKM0(); SCHED0();
    __builtin_amdgcn_s_setprio(1); mfma16(af0, bf0, acc, 0, 0); __builtin_amdgcn_s_setprio(0);
    FENCE(); BAR();

    ldsA(Ar1, 1, fr, cx, af1);
    if (nl) STAGE(e + 3, 0);
    FENCE(); BAR(); LGKM0(); SCHED0();
    __builtin_amdgcn_s_setprio(1); mfma16(af1, bf0, acc, 1, 0); __builtin_amdgcn_s_setprio(0);
    FENCE(); BAR();

    ldsB(Br1, 1, rbB, fr, cx, bf1);
    if (nl) STAGE(e + 3, 1);
    FENCE(); BAR(); LGKM0(); SCHED0();
    __builtin_amdgcn_s_setprio(1); mfma16(af1, bf1, acc, 1, 1); __builtin_amdgcn_s_setprio(0);
    FENCE(); BAR();

    if (nl) STAGE(e + 3, 2);
    FENCE(); BAR(); LGKM0(); SCHED0();
    __builtin_amdgcn_s_setprio(1); mfma16(af0, bf1, acc, 0, 1); __builtin_amdgcn_s_setprio(0);
    if (nl) { VMCNT(6); }                      // tile e+2 resident; e+3 h0..h2 in flight
    FENCE(); BAR();
  }
#undef STAGE

  // epilogue: C/D layout col = lane&15, row = fq*4 + reg  (verified m89/m91)
  const int rowb = bm * 256 + wr * 128 + fq * 4;
  const int colb = bn * 256 + wc * 64 + fr;
  #pragma unroll
  for (int m = 0; m < 8; ++m) {
    #pragma unroll
    for (int nf = 0; nf < 4; ++nf) {
      #pragma unroll
      for (int ii = 0; ii < 4; ++ii) {
        const size_t idx = (size_t)(rowb + m * 16 + ii) * NOUT + (colb + nf * 16);
        float v = acc[m][nf][ii];
        if (EPI == 0) {
          ((short*)Cv)[idx] = f2bf(v / (1.0f + __expf(-v)));
        } else if (EPI == 1) {
          float sg = bf2f(((const short*)Cv)[idx]);
          ((short*)Cv)[idx] = f2bf(v * sg);
        } else {
          ((float*)Cv)[idx] = v;
        }
      }
    }
  }
}

extern "C" void kernel_launch(void* const* d_in, const int* in_sizes, int n_in,
                              void* d_out, int out_size, void* d_ws, size_t ws_size,
                              hipStream_t stream) {
  const float* x      = (const float*)d_in[0];
  // d_in[1] = H (Sylvester Hadamard; symmetric -> computed via FWHT, unused)
  const float* gate_w = (const float*)d_in[2];
  const float* up_w   = (const float*)d_in[3];
  const float* down_w = (const float*)d_in[4];
  float* out = (float*)d_out;

  short* xr = (short*)d_ws;                       // [TOKENS, HIDDEN] bf16
  short* gw = xr + (size_t)TOKENS * HIDDEN;       // [INTER, HIDDEN] bf16
  short* uw = gw + (size_t)INTER * HIDDEN;        // [INTER, HIDDEN] bf16
  short* dw = uw + (size_t)INTER * HIDDEN;        // [HIDDEN, INTER] bf16
  short* sg = dw + (size_t)HIDDEN * INTER;        // [TOKENS, INTER] bf16: silu(g), then h

  const int n4 = (INTER * HIDDEN) / 4;
  cvt_w<<<(n4 + 255) / 256, 256, 0, stream>>>(gate_w, gw, n4);
  cvt_w<<<(n4 + 255) / 256, 256, 0, stream>>>(up_w, uw, n4);
  cvt_w<<<(n4 + 255) / 256, 256, 0, stream>>>(down_w, dw, n4);

  fwht_cast<<<2048, 256, 0, stream>>>(x, xr);

  // sg = silu(xr @ gw^T)
  gemm256<HIDDEN, INTER / 256, INTER, 0>
      <<<(TOKENS / 256) * (INTER / 256), 512, 0, stream>>>(xr, gw, sg);
  // sg = sg * (xr @ uw^T)   (in place)
  gemm256<HIDDEN, INTER / 256, INTER, 1>
      <<<(TOKENS / 256) * (INTER / 256), 512, 0, stream>>>(xr, uw, sg);
  // out = sg @ dw^T  (fp32)
  gemm256<INTER, HIDDEN / 256, HIDDEN, 2>
      <<<(TOKENS / 256) * (HIDDEN / 256), 512, 0, stream>>>(sg, dw, out);
}

// Round 5
// 695.283 us; speedup vs baseline: 1.8129x; 1.0354x over previous
//
#include <hip/hip_runtime.h>
#include <math.h>

#define HIDDEN 2048
#define INTER  5632
#define TOKENS 8192

typedef __attribute__((ext_vector_type(8))) short bf16x8;
typedef __attribute__((ext_vector_type(4))) float f32x4;
typedef __attribute__((ext_vector_type(4))) short short4v;

#define FENCE() asm volatile("" ::: "memory")
#define BAR()   __builtin_amdgcn_s_barrier()
#define VMCNT(n) asm volatile("s_waitcnt vmcnt(" #n ")" ::: "memory")
#define PRIO1() __builtin_amdgcn_s_setprio(1)
#define PRIO0() __builtin_amdgcn_s_setprio(0)
// barrier with compiler memory fences on both sides (loads must not cross s_barrier)
#define BARF()  do { FENCE(); BAR(); FENCE(); } while (0)

__device__ __forceinline__ short f2bf(float f) {
  union { float f; unsigned u; } v; v.f = f;
  unsigned r = v.u + 0x7fffu + ((v.u >> 16) & 1u);
  return (short)(r >> 16);
}
__device__ __forceinline__ float bf2f(short s) {
  union { unsigned u; float f; } v; v.u = ((unsigned)(unsigned short)s) << 16;
  return v.f;
}

// ---------------- fused fp32 -> bf16 cast of all three weights ----------------
// dst is gw; uw, dw are contiguous after it in ws.
__global__ __launch_bounds__(256) void cvt_all(const float* __restrict__ g,
                                               const float* __restrict__ u,
                                               const float* __restrict__ d,
                                               short* __restrict__ dst, int n4) {
  int i = blockIdx.x * 256 + threadIdx.x;   // [0, 3*n4)
  const float* src; int off;
  if (i < n4)            { src = g; off = i; }
  else if (i < 2 * n4)   { src = u; off = i - n4; }
  else                   { src = d; off = i - 2 * n4; }
  float4 v = ((const float4*)src)[off];
  short4v o;
  o[0] = f2bf(v.x); o[1] = f2bf(v.y); o[2] = f2bf(v.z); o[3] = f2bf(v.w);
  ((short4v*)dst)[i] = o;
}

// ---------------- FWHT per row (x @ H^T == FWHT(x)/sqrt(H)) + bf16 cast ----------------
__global__ __launch_bounds__(256) void fwht_cast(const float* __restrict__ X,
                                                 short* __restrict__ Xr) {
  __shared__ __align__(16) float row[HIDDEN];
  const int tid = threadIdx.x;
  for (int r = blockIdx.x; r < TOKENS; r += gridDim.x) {
    const float4* src = (const float4*)(X + (size_t)r * HIDDEN);
    float4 va = src[tid];
    float4 vb = src[tid + 256];
    float a[8] = {va.x, va.y, va.z, va.w, vb.x, vb.y, vb.z, vb.w};
    #pragma unroll
    for (int j = 0; j < 4; ++j) { float s = a[j] + a[j+4], d = a[j] - a[j+4]; a[j] = s; a[j+4] = d; }
    #pragma unroll
    for (int j = 0; j < 8; j += 2) { float s = a[j] + a[j+1], d = a[j] - a[j+1]; a[j] = s; a[j+1] = d; }
    #pragma unroll
    for (int h = 0; h < 8; h += 4) {
      { float s = a[h]   + a[h+2], d = a[h]   - a[h+2]; a[h]   = s; a[h+2] = d; }
      { float s = a[h+1] + a[h+3], d = a[h+1] - a[h+3]; a[h+1] = s; a[h+3] = d; }
    }
    ((float4*)row)[tid]       = make_float4(a[0], a[1], a[2], a[3]);
    ((float4*)row)[tid + 256] = make_float4(a[4], a[5], a[6], a[7]);
    __syncthreads();
    for (int s = 4; s <= 512; s <<= 1) {
      #pragma unroll
      for (int pp = 0; pp < 4; ++pp) {
        int p = tid + pp * 256;
        int i = ((p & ~(s - 1)) << 1) | (p & (s - 1));
        float x0 = row[i], x1 = row[i + s];
        row[i] = x0 + x1; row[i + s] = x0 - x1;
      }
      __syncthreads();
    }
    const float scale = 0.02209708691207961f; // 1/sqrt(2048)
    float4 wa = ((float4*)row)[tid];
    float4 wb = ((float4*)row)[tid + 256];
    short4v oa, ob;
    oa[0] = f2bf(wa.x * scale); oa[1] = f2bf(wa.y * scale);
    oa[2] = f2bf(wa.z * scale); oa[3] = f2bf(wa.w * scale);
    ob[0] = f2bf(wb.x * scale); ob[1] = f2bf(wb.y * scale);
    ob[2] = f2bf(wb.z * scale); ob[3] = f2bf(wb.w * scale);
    short* dst = Xr + (size_t)r * HIDDEN;
    ((short4v*)dst)[tid]       = oa;
    ((short4v*)dst)[tid + 256] = ob;
    __syncthreads();
  }
}

// ---------------- shared GEMM pieces ----------------
// Stage a 128x64 bf16 half-tile into one 8 KiB LDS region (linear dest,
// inverse-XOR-swizzled global source: LDS slot s holds global 16B-chunk
// ((s&7) ^ ((s>>3)&7)) of row s>>3).
__device__ __forceinline__ void stage_half(const short* __restrict__ gbase, int ldK, int kt,
                                           short* region, int tid) {
  const int w = tid >> 6;
  #pragma unroll
  for (int j = 0; j < 2; ++j) {
    const int slot = tid + j * 512;
    const int row  = slot >> 3;
    const int cg   = (slot & 7) ^ (row & 7);
    const short* gp = gbase + (size_t)row * ldK + kt * 64 + cg * 8;
    short* lp = region + w * 512 + j * 4096;   // wave-uniform base; HW adds lane*16B
    __builtin_amdgcn_global_load_lds((const __attribute__((address_space(1))) void*)gp,
                                     (__attribute__((address_space(3))) void*)lp, 16, 0, 0);
  }
}

// A fragments: 8 x b128 (4 m-frags x 2 k-chunks) for token-quadrant qm.
__device__ __forceinline__ void ldsA(const short* rg, int qm, int fr, const int* cx,
                                     bf16x8* dst) {
  #pragma unroll
  for (int i = 0; i < 4; ++i)
    #pragma unroll
    for (int kk = 0; kk < 2; ++kk)
      dst[i * 2 + kk] = *(const bf16x8*)(rg + (qm * 64 + i * 16 + fr) * 64 + cx[kk]);
}

// B fragments, 64-col wave slice (down kernel): rows rb + qn*32 + n*16 + fr.
__device__ __forceinline__ void ldsB(const short* rg, int qn, int rb, int fr, const int* cx,
                                     bf16x8* dst) {
  #pragma unroll
  for (int n = 0; n < 2; ++n)
    #pragma unroll
    for (int kk = 0; kk < 2; ++kk)
      dst[n * 2 + kk] = *(const bf16x8*)(rg + (rb + qn * 32 + n * 16 + fr) * 64 + cx[kk]);
}

// B fragments, 32-col wave slice (fused kernel): rows wc*32 + n*16 + fr.
__device__ __forceinline__ void ldsB32(const short* rg, int wc, int fr, const int* cx,
                                       bf16x8* dst) {
  #pragma unroll
  for (int n = 0; n < 2; ++n)
    #pragma unroll
    for (int kk = 0; kk < 2; ++kk)
      dst[n * 2 + kk] = *(const bf16x8*)(rg + (wc * 32 + n * 16 + fr) * 64 + cx[kk]);
}

__device__ __forceinline__ void mfma_ph2(const bf16x8* a, const bf16x8* b,
                                         f32x4 (&acc)[8][2], int qm) {
  #pragma unroll
  for (int i = 0; i < 4; ++i)
    #pragma unroll
    for (int n = 0; n < 2; ++n)
      #pragma unroll
      for (int kk = 0; kk < 2; ++kk)
        acc[qm * 4 + i][n] = __builtin_amdgcn_mfma_f32_16x16x32_bf16(
            a[i * 2 + kk], b[n * 2 + kk], acc[qm * 4 + i][n], 0, 0, 0);
}

__device__ __forceinline__ void mfma_ph4(const bf16x8* a, const bf16x8* b,
                                         f32x4 (&acc)[8][4], int qm, int qn) {
  #pragma unroll
  for (int i = 0; i < 4; ++i)
    #pragma unroll
    for (int n = 0; n < 2; ++n)
      #pragma unroll
      for (int kk = 0; kk < 2; ++kk)
        acc[qm * 4 + i][qn * 2 + n] = __builtin_amdgcn_mfma_f32_16x16x32_bf16(
            a[i * 2 + kk], b[n * 2 + kk], acc[qm * 4 + i][qn * 2 + n], 0, 0, 0);
}

// ---------------- fused gate+up GEMM: h = silu(x@gw^T) * (x@uw^T) ----------------
// Block output: 256 tokens x 128 channels. Regions: 0,1 = A halves; 2 = gate B
// (128 rows); 3 = up B (128 rows). Register-subtile pipelined: P1 issues
// af0+bg+af1; P2 issues bu; compiler inserts counted lgkm waits.
template<int LDK, int NBN>
__global__ __launch_bounds__(512, 2) void gemm_gateup(const short* __restrict__ A,
                                                      const short* __restrict__ Bg,
                                                      const short* __restrict__ Bu,
                                                      short* __restrict__ Hb) {
  constexpr int NKT = LDK / 64;
  __shared__ __align__(16) short lds[2][4][8192];   // 128 KiB

  const int tid  = threadIdx.x;
  const int lane = tid & 63, wv = tid >> 6;
  const int wr = wv >> 2, wc = wv & 3;              // wave: 128 tokens x 32 channels (g+u)
  const int fr = lane & 15, fq = lane >> 4;
  const int x7 = fr & 7;
  const int cx[2] = { (fq ^ x7) * 8, ((4 + fq) ^ x7) * 8 };

  const int nwg = gridDim.x;                        // 1408, %8==0
  const int swz = (blockIdx.x & 7) * (nwg >> 3) + (blockIdx.x >> 3);
  const int bm = swz / NBN, bn = swz % NBN;

  const short* Ab[2] = { A + (size_t)(bm * 256) * LDK, A + (size_t)(bm * 256 + 128) * LDK };
  const short* Bgb = Bg + (size_t)(bn * 128) * LDK;
  const short* Bub = Bu + (size_t)(bn * 128) * LDK;

#define STAGE(kt_, rg_) stage_half((rg_) == 0 ? Ab[0] : (rg_) == 1 ? Ab[1] : \
                                   (rg_) == 2 ? Bgb : Bub, LDK, (kt_), \
                                   &lds[(kt_) & 1][(rg_)][0], tid)

  f32x4 accG[8][2] = {};
  f32x4 accU[8][2] = {};

  STAGE(0, 0); STAGE(0, 1); STAGE(0, 2); STAGE(0, 3);
  STAGE(1, 0); STAGE(1, 1); STAGE(1, 2);
  VMCNT(6);
  BARF();

  bf16x8 af0[8], af1[8], bg[4], bu[4];

  for (int kt = 0; kt < NKT; ++kt) {
    const bool nl1 = (kt + 1 < NKT), nl2 = (kt + 2 < NKT);
    const short* Ar  = &lds[kt & 1][wr][0];
    const short* Bgr = &lds[kt & 1][2][0];
    const short* Bur = &lds[kt & 1][3][0];

    // P1: af0+bg+af1 issued; MFMA waits only af0/bg (af1 flies under it)
    ldsA(Ar, 0, fr, cx, af0);
    ldsB32(Bgr, wc, fr, cx, bg);
    ldsA(Ar, 1, fr, cx, af1);
    if (nl1) STAGE(kt + 1, 3);
    BARF();
    PRIO1(); mfma_ph2(af0, bg, accG, 0); PRIO0();
    BARF();

    // P2: bu issued; MFMA waits af1 (lgkm counted)
    ldsB32(Bur, wc, fr, cx, bu);
    if (nl2) STAGE(kt + 2, 0);
    BARF();
    PRIO1(); mfma_ph2(af1, bg, accG, 1); PRIO0();
    BARF();

    // P3: MFMA waits bu
    if (nl2) STAGE(kt + 2, 1);
    BARF();
    PRIO1(); mfma_ph2(af1, bu, accU, 1); PRIO0();
    BARF();

    // P4: all operands in registers
    if (nl2) STAGE(kt + 2, 2);
    BARF();
    PRIO1(); mfma_ph2(af0, bu, accU, 0); PRIO0();
    if (nl2) { VMCNT(6); } else if (nl1) { VMCNT(0); }
    BARF();
  }
#undef STAGE

  // epilogue: C/D layout col = lane&15, row = fq*4 + reg
  const int rowb = bm * 256 + wr * 128 + fq * 4;
  const int colb = bn * 128 + wc * 32 + fr;
  #pragma unroll
  for (int m = 0; m < 8; ++m) {
    #pragma unroll
    for (int nf = 0; nf < 2; ++nf) {
      #pragma unroll
      for (int ii = 0; ii < 4; ++ii) {
        const size_t idx = (size_t)(rowb + m * 16 + ii) * INTER + (colb + nf * 16);
        float g = accG[m][nf][ii];
        float u = accU[m][nf][ii];
        Hb[idx] = f2bf(g * u / (1.0f + __expf(-g)));
      }
    }
  }
}

// ---------------- down GEMM: out = h @ dw^T (fp32 out) ----------------
template<int LDK, int NBN>
__global__ __launch_bounds__(512, 2) void gemm_down(const short* __restrict__ A,
                                                    const short* __restrict__ B,
                                                    float* __restrict__ Out) {
  constexpr int NKT = LDK / 64;
  __shared__ __align__(16) short lds[2][4][8192];

  const int tid  = threadIdx.x;
  const int lane = tid & 63, wv = tid >> 6;
  const int wr = wv >> 2, wc = wv & 3;              // wave: 128 x 64 output
  const int fr = lane & 15, fq = lane >> 4;
  const int x7 = fr & 7;
  const int cx[2] = { (fq ^ x7) * 8, ((4 + fq) ^ x7) * 8 };
  const int rbB = (wc & 1) * 64;

  const int nwg = gridDim.x;                        // 256, %8==0
  const int swz = (blockIdx.x & 7) * (nwg >> 3) + (blockIdx.x >> 3);
  const int bm = swz / NBN, bn = swz % NBN;

  const short* Ab[2] = { A + (size_t)(bm * 256) * LDK, A + (size_t)(bm * 256 + 128) * LDK };
  const short* Bb[2] = { B + (size_t)(bn * 256) * LDK, B + (size_t)(bn * 256 + 128) * LDK };

#define STAGE(kt_, rg_) stage_half((rg_) < 2 ? Ab[(rg_)] : Bb[(rg_) - 2], LDK, (kt_), \
                                   &lds[(kt_) & 1][(rg_)][0], tid)

  f32x4 acc[8][4] = {};

  STAGE(0, 0); STAGE(0, 1); STAGE(0, 2); STAGE(0, 3);
  STAGE(1, 0); STAGE(1, 1); STAGE(1, 2);
  VMCNT(6);
  BARF();

  bf16x8 af0[8], af1[8], bf0[4], bf1[4];

  for (int kt = 0; kt < NKT; ++kt) {
    const bool nl1 = (kt + 1 < NKT), nl2 = (kt + 2 < NKT);
    const short* Ar = &lds[kt & 1][wr][0];
    const short* Br = &lds[kt & 1][2 + (wc >> 1)][0];

    // P1
    ldsA(Ar, 0, fr, cx, af0);
    ldsB(Br, 0, rbB, fr, cx, bf0);
    ldsA(Ar, 1, fr, cx, af1);
    if (nl1) STAGE(kt + 1, 3);
    BARF();
    PRIO1(); mfma_ph4(af0, bf0, acc, 0, 0); PRIO0();
    BARF();

    // P2
    ldsB(Br, 1, rbB, fr, cx, bf1);
    if (nl2) STAGE(kt + 2, 0);
    BARF();
    PRIO1(); mfma_ph4(af1, bf0, acc, 1, 0); PRIO0();
    BARF();

    // P3
    if (nl2) STAGE(kt + 2, 1);
    BARF();
    PRIO1(); mfma_ph4(af1, bf1, acc, 1, 1); PRIO0();
    BARF();

    // P4
    if (nl2) STAGE(kt + 2, 2);
    BARF();
    PRIO1(); mfma_ph4(af0, bf1, acc, 0, 1); PRIO0();
    if (nl2) { VMCNT(6); } else if (nl1) { VMCNT(0); }
    BARF();
  }
#undef STAGE

  const int rowb = bm * 256 + wr * 128 + fq * 4;
  const int colb = bn * 256 + wc * 64 + fr;
  #pragma unroll
  for (int m = 0; m < 8; ++m) {
    #pragma unroll
    for (int nf = 0; nf < 4; ++nf) {
      #pragma unroll
      for (int ii = 0; ii < 4; ++ii) {
        Out[(size_t)(rowb + m * 16 + ii) * HIDDEN + (colb + nf * 16)] = acc[m][nf][ii];
      }
    }
  }
}

extern "C" void kernel_launch(void* const* d_in, const int* in_sizes, int n_in,
                              void* d_out, int out_size, void* d_ws, size_t ws_size,
                              hipStream_t stream) {
  const float* x      = (const float*)d_in[0];
  // d_in[1] = H (Sylvester Hadamard; symmetric -> computed via FWHT, unused)
  const float* gate_w = (const float*)d_in[2];
  const float* up_w   = (const float*)d_in[3];
  const float* down_w = (const float*)d_in[4];
  float* out = (float*)d_out;

  short* xr = (short*)d_ws;                       // [TOKENS, HIDDEN] bf16
  short* gw = xr + (size_t)TOKENS * HIDDEN;       // [INTER, HIDDEN] bf16
  short* uw = gw + (size_t)INTER * HIDDEN;        // [INTER, HIDDEN] bf16
  short* dw = uw + (size_t)INTER * HIDDEN;        // [HIDDEN, INTER] bf16
  short* hb = dw + (size_t)HIDDEN * INTER;        // [TOKENS, INTER] bf16

  const int n4 = (INTER * HIDDEN) / 4;            // 2,883,584 (all 3 weights same elem count)
  cvt_all<<<(3 * n4) / 256, 256, 0, stream>>>(gate_w, up_w, down_w, gw, n4);

  fwht_cast<<<4096, 256, 0, stream>>>(x, xr);

  // hb = silu(xr @ gw^T) * (xr @ uw^T)
  gemm_gateup<HIDDEN, INTER / 128>
      <<<(TOKENS / 256) * (INTER / 128), 512, 0, stream>>>(xr, gw, uw, hb);
  // out = hb @ dw^T  (fp32)
  gemm_down<INTER, HIDDEN / 256>
      <<<(TOKENS / 256) * (HIDDEN / 256), 512, 0, stream>>>(hb, dw, out);
}